// Round 2
// baseline (610.336 us; speedup 1.0000x reference)
//
#include <hip/hip_runtime.h>
#include <hip/hip_bf16.h>

#define BQ   16
#define BK2  32     // 2B
#define SEQ  256
#define HD   768
#define NKT  24     // HD / 32 K-tiles

typedef __attribute__((ext_vector_type(8))) short bf16x8;
typedef __attribute__((ext_vector_type(4))) float f32x4;

__device__ __forceinline__ void glds16(const unsigned short* g, unsigned short* l) {
    __builtin_amdgcn_global_load_lds(
        (const __attribute__((address_space(1))) unsigned int*)g,
        (__attribute__((address_space(3))) unsigned int*)l, 16, 0, 0);
}

// branch-free RNE fp32->bf16, packed two at a time
__device__ __forceinline__ unsigned int pack2_bf16(float a, float b) {
    unsigned ua = __float_as_uint(a), ub = __float_as_uint(b);
    ua += 0x7FFFu + ((ua >> 16) & 1u);
    ub += 0x7FFFu + ((ub >> 16) & 1u);
    return (ua >> 16) | (ub & 0xFFFF0000u);
}

// ---------------- Phase 1: fp32 l2-normalize -> bf16 ----------------------
__global__ __launch_bounds__(256) void norm_kernel(
    const float* __restrict__ q, const float* __restrict__ k,
    unsigned short* __restrict__ qn, unsigned short* __restrict__ kn)
{
    int row  = blockIdx.x * 4 + (threadIdx.x >> 6);
    int lane = threadIdx.x & 63;
    const int NQ = BQ * SEQ;
    const float* src = (row < NQ) ? q + (size_t)row * HD
                                  : k + (size_t)(row - NQ) * HD;
    unsigned int* dst = (unsigned int*)((row < NQ) ? qn + (size_t)row * HD
                                                   : kn + (size_t)(row - NQ) * HD);
    float4 v[3];
    float ss = 0.f;
#pragma unroll
    for (int c = 0; c < 3; ++c) {
        v[c] = ((const float4*)src)[lane + 64 * c];
        ss += v[c].x * v[c].x + v[c].y * v[c].y + v[c].z * v[c].z + v[c].w * v[c].w;
    }
#pragma unroll
    for (int m = 1; m < 64; m <<= 1) ss += __shfl_xor(ss, m, 64);
    float inv = rsqrtf(fmaxf(ss, 1e-24f));
#pragma unroll
    for (int c = 0; c < 3; ++c) {
        uint2 o = make_uint2(pack2_bf16(v[c].x * inv, v[c].y * inv),
                             pack2_bf16(v[c].z * inv, v[c].w * inv));
        ((uint2*)dst)[lane + 64 * c] = o;
    }
}

// ---------------- Phase 2: block = (j, i) covering FULL 256 s x 256 t -----
// 8 waves as 2(s) x 4(t), each wave owns a 128x64 tile (acc[8][4]).
// BK=32 double-buffered glds staging, counted-vmcnt pipeline, setprio.
// One block per output element -> direct store, no atomics.
__global__ __launch_bounds__(512, 4) void li_kernel(
    const unsigned short* __restrict__ qn, const unsigned short* __restrict__ kn,
    const float* __restrict__ g_ls, const float* __restrict__ g_ar,
    const int* __restrict__ q_mask, const int* __restrict__ k_mask,
    float* __restrict__ out)
{
    const int j  = blockIdx.x, i = blockIdx.y;
    const int tid  = threadIdx.x;
    const int w    = tid >> 6, lane = tid & 63;
    const int ln   = lane & 15, lg = lane >> 4;
    const int wsd  = w >> 2, wt = w & 3;     // wave = (s-half, t-quarter)

    // BK=32: row = 32 cols = 64 B. One glds (1 KB) = 16 rows. ds_read_b128
    // with row=ln, chunk=lg covers a full contiguous 1 KB region -> no
    // bank conflicts, no swizzle needed.
    __shared__ __align__(16) unsigned short As[2 * 256 * 32];  // 32 KB dbuf
    __shared__ __align__(16) unsigned short Bs[2 * 256 * 32];  // 32 KB dbuf
    __shared__ float w2[SEQ];      // scale * exp(-alpha*d)
    __shared__ float kmB[SEQ];
    __shared__ float red[8];

    float a0 = g_ar[0];
    float alpha = (a0 > 0.f) ? a0 : 0.01f * a0;        // leaky_relu
    float scale = __expf(g_ls[0]);
    if (tid < 256) w2[tid] = scale * __expf(-alpha * (float)tid);
    else           kmB[tid - 256] = (k_mask[j * SEQ + (tid - 256)] != 0) ? 1.f : 0.f;

    // staging: wave w owns rows [w*32, w*32+32) of both A and B panels.
    // lane l covers row base + (l>>2), 16-B chunk (l&3).
    const unsigned short* aq = qn + ((size_t)i * SEQ + w * 32 + (lane >> 2)) * HD + (lane & 3) * 8;
    const unsigned short* bq = kn + ((size_t)j * SEQ + w * 32 + (lane >> 2)) * HD + (lane & 3) * 8;

#define STAGE(kt, b) do {                                            \
        const int kk_ = (kt) * 32;                                   \
        unsigned short* al_ = As + (b) * 8192 + w * 1024;            \
        unsigned short* bl_ = Bs + (b) * 8192 + w * 1024;            \
        glds16(aq + kk_,           al_);                             \
        glds16(aq + kk_ + 16 * HD, al_ + 512);                       \
        glds16(bq + kk_,           bl_);                             \
        glds16(bq + kk_ + 16 * HD, bl_ + 512);                       \
    } while (0)

    f32x4 acc[8][4];
    const f32x4 zero4 = {0.f, 0.f, 0.f, 0.f};
#pragma unroll
    for (int a = 0; a < 8; ++a)
#pragma unroll
        for (int b = 0; b < 4; ++b) acc[a][b] = zero4;

    // prologue: fill both buffers (8 glds in flight per wave)
    STAGE(0, 0);
    STAGE(1, 1);

#pragma unroll 1
    for (int kt = 0; kt < NKT; ++kt) {
        const int cur = kt & 1;
        // tile kt landed (its 4 glds are oldest); keep tile kt+1 in flight
        if (kt == NKT - 1) asm volatile("s_waitcnt vmcnt(0)" ::: "memory");
        else               asm volatile("s_waitcnt vmcnt(4)" ::: "memory");
        __builtin_amdgcn_sched_barrier(0);
        __builtin_amdgcn_s_barrier();      // all waves' tile-kt writes visible

        const bf16x8* A8 = (const bf16x8*)(As + cur * 8192);
        const bf16x8* B8 = (const bf16x8*)(Bs + cur * 8192);
        bf16x8 af[8], bfr[4];
#pragma unroll
        for (int rm = 0; rm < 8; ++rm)
            af[rm] = A8[(wsd * 128 + rm * 16 + ln) * 4 + lg];
#pragma unroll
        for (int cn = 0; cn < 4; ++cn)
            bfr[cn] = B8[(wt * 64 + cn * 16 + ln) * 4 + lg];

        __builtin_amdgcn_s_setprio(1);
#pragma unroll
        for (int rm = 0; rm < 8; ++rm)
#pragma unroll
            for (int cn = 0; cn < 4; ++cn)
                acc[rm][cn] = __builtin_amdgcn_mfma_f32_16x16x32_bf16(
                    af[rm], bfr[cn], acc[rm][cn], 0, 0, 0);
        __builtin_amdgcn_s_setprio(0);

        __builtin_amdgcn_s_barrier();      // all waves done reading buf[cur]
        if (kt + 2 < NKT) STAGE(kt + 2, cur);   // 2-deep prefetch into freed buf
    }
#undef STAGE

    // epilogue: C/D layout col=ln (t), row=lg*4+r (s)
    __syncthreads();                    // all LDS traffic drained; reuse As
    float* zs  = (float*)As;            // [256][4] Z partials per (srow, wt)
    float* wsc = zs + 1024;             // [256][4] W partials

#pragma unroll
    for (int rm = 0; rm < 8; ++rm)
#pragma unroll
        for (int r = 0; r < 4; ++r) {
            int s = wsd * 128 + rm * 16 + lg * 4 + r;     // global s (full 256)
            float ze = 0.f, we = 0.f;
#pragma unroll
            for (int cn = 0; cn < 4; ++cn) {
                int t = wt * 64 + cn * 16 + ln;           // global t (full 256)
                float sim = acc[rm][cn][r];
                int d = s - t; d = (d < 0) ? -d : d;
                float e = kmB[t] * __expf(sim * w2[d]);
                ze += e;
                we = fmaf(e, sim, we);
            }
#pragma unroll
            for (int m = 1; m < 16; m <<= 1) {            // reduce over t-16 lanes
                ze += __shfl_xor(ze, m, 64);
                we += __shfl_xor(we, m, 64);
            }
            if (ln == 0) { zs[s * 4 + wt] = ze; wsc[s * 4 + wt] = we; }
        }
    __syncthreads();

    float part = 0.f;
    if (tid < 256) {
        const float4 Z4 = ((const float4*)zs)[tid];
        const float4 W4 = ((const float4*)wsc)[tid];
        float Z = Z4.x + Z4.y + Z4.z + Z4.w;
        float W = W4.x + W4.y + W4.z + W4.w;
        float pt = (Z > 0.f) ? (W / Z) : 0.f;
        part = pt * (float)q_mask[i * SEQ + tid];
    }
#pragma unroll
    for (int m = 1; m < 64; m <<= 1) part += __shfl_xor(part, m, 64);
    if (lane == 0) red[w] = part;
    __syncthreads();
    if (tid == 0) {
        float tot = red[0] + red[1] + red[2] + red[3]
                  + red[4] + red[5] + red[6] + red[7];
        out[i * BK2 + j] = tot;     // exactly one block per output element
    }
}

extern "C" void kernel_launch(void* const* d_in, const int* in_sizes, int n_in,
                              void* d_out, int out_size, void* d_ws, size_t ws_size,
                              hipStream_t stream) {
    const float* q  = (const float*)d_in[0];   // [16,256,768] f32
    const float* k  = (const float*)d_in[1];   // [32,256,768] f32
    const float* ls = (const float*)d_in[2];   // scalar
    const float* ar = (const float*)d_in[3];   // scalar
    const int* qm   = (const int*)d_in[4];     // [16,256]
    const int* km   = (const int*)d_in[5];     // [32,256]
    float* out      = (float*)d_out;           // [16,32] f32

    unsigned short* qn = (unsigned short*)d_ws;            // 16*256*768 bf16
    unsigned short* kn = qn + (size_t)BQ * SEQ * HD;       // 32*256*768 bf16

    norm_kernel<<<(BQ + BK2) * SEQ / 4, 256, 0, stream>>>(q, k, qn, kn);
    li_kernel<<<dim3(BK2, BQ), 512, 0, stream>>>(qn, kn, ls, ar, qm, km, (float*)d_out);
}

// Round 3
// 161.279 us; speedup vs baseline: 3.7844x; 3.7844x over previous
//
#include <hip/hip_runtime.h>
#include <hip/hip_bf16.h>

#define BQ   16
#define BK2  32     // 2B
#define SEQ  256
#define HD   768
#define NKT  24     // HD / 32 K-tiles

typedef __attribute__((ext_vector_type(8))) short bf16x8;
typedef __attribute__((ext_vector_type(4))) float f32x4;

__device__ __forceinline__ void glds16(const unsigned short* g, unsigned short* l) {
    __builtin_amdgcn_global_load_lds(
        (const __attribute__((address_space(1))) unsigned int*)g,
        (__attribute__((address_space(3))) unsigned int*)l, 16, 0, 0);
}

// branch-free RNE fp32->bf16, packed two at a time
__device__ __forceinline__ unsigned int pack2_bf16(float a, float b) {
    unsigned ua = __float_as_uint(a), ub = __float_as_uint(b);
    ua += 0x7FFFu + ((ua >> 16) & 1u);
    ub += 0x7FFFu + ((ub >> 16) & 1u);
    return (ua >> 16) | (ub & 0xFFFF0000u);
}

// ---------------- Phase 1: fp32 l2-normalize -> bf16 ----------------------
__global__ __launch_bounds__(256) void norm_kernel(
    const float* __restrict__ q, const float* __restrict__ k,
    unsigned short* __restrict__ qn, unsigned short* __restrict__ kn)
{
    int row  = blockIdx.x * 4 + (threadIdx.x >> 6);
    int lane = threadIdx.x & 63;
    const int NQ = BQ * SEQ;
    const float* src = (row < NQ) ? q + (size_t)row * HD
                                  : k + (size_t)(row - NQ) * HD;
    unsigned int* dst = (unsigned int*)((row < NQ) ? qn + (size_t)row * HD
                                                   : kn + (size_t)(row - NQ) * HD);
    float4 v[3];
    float ss = 0.f;
#pragma unroll
    for (int c = 0; c < 3; ++c) {
        v[c] = ((const float4*)src)[lane + 64 * c];
        ss += v[c].x * v[c].x + v[c].y * v[c].y + v[c].z * v[c].z + v[c].w * v[c].w;
    }
#pragma unroll
    for (int m = 1; m < 64; m <<= 1) ss += __shfl_xor(ss, m, 64);
    float inv = rsqrtf(fmaxf(ss, 1e-24f));
#pragma unroll
    for (int c = 0; c < 3; ++c) {
        uint2 o = make_uint2(pack2_bf16(v[c].x * inv, v[c].y * inv),
                             pack2_bf16(v[c].z * inv, v[c].w * inv));
        ((uint2*)dst)[lane + 64 * c] = o;
    }
}

// ---------------- Phase 2: block = (j, i) covering FULL 256 s x 256 t -----
// 8 waves as 2(s) x 4(t), each wave owns a 128x64 tile (acc[8][4] = 128 VGPR
// -> __launch_bounds__(512,2): 256-VGPR budget, NO spills, 1 block/CU).
// BK=32 double-buffered glds staging, counted-vmcnt pipeline, setprio.
// LDS chunk swizzle: logical 16B-chunk c of row r stored at slot c^((r>>1)&3)
// (pre-swizzled global source, linear glds dest; same XOR on read -> 2-way max).
// One block per output element -> direct store, no atomics.
__global__ __launch_bounds__(512, 2) void li_kernel(
    const unsigned short* __restrict__ qn, const unsigned short* __restrict__ kn,
    const float* __restrict__ g_ls, const float* __restrict__ g_ar,
    const int* __restrict__ q_mask, const int* __restrict__ k_mask,
    float* __restrict__ out)
{
    // XCD-aware remap: 1-D grid 512, XCD = bid&7 (round-robin heuristic).
    // Each XCD owns an 8x8 (i,j) tile -> co-resident panels fit its 4MB L2.
    const int bid = blockIdx.x;
    const int xcd = bid & 7, q8 = bid >> 3;
    const int i = (xcd >> 2) * 8 + (q8 >> 3);   // 0..15
    const int j = (xcd & 3) * 8 + (q8 & 7);     // 0..31

    const int tid  = threadIdx.x;
    const int w    = tid >> 6, lane = tid & 63;
    const int ln   = lane & 15, lg = lane >> 4;
    const int wsd  = w >> 2, wt = w & 3;     // wave = (s-half, t-quarter)

    __shared__ __align__(16) unsigned short As[2 * 256 * 32];  // 32 KB dbuf
    __shared__ __align__(16) unsigned short Bs[2 * 256 * 32];  // 32 KB dbuf
    __shared__ float w2[SEQ];      // scale * exp(-alpha*d)
    __shared__ float kmB[SEQ];
    __shared__ float red[8];

    float a0 = g_ar[0];
    float alpha = (a0 > 0.f) ? a0 : 0.01f * a0;        // leaky_relu
    float scale = __expf(g_ls[0]);
    if (tid < 256) w2[tid] = scale * __expf(-alpha * (float)tid);
    else           kmB[tid - 256] = (k_mask[j * SEQ + (tid - 256)] != 0) ? 1.f : 0.f;

    // staging: wave w owns rows [w*32, w*32+32). lane l covers row base+(l>>2),
    // LDS slot (l&3); source chunk = (l&3) ^ f(row),  f(r) = (r>>1)&3.
    const int srow = lane >> 2;                       // 0..15 within 16-row group
    const int gch  = (lane & 3) ^ ((srow >> 1) & 3);  // pre-swizzled global chunk
    const unsigned short* aq = qn + ((size_t)i * SEQ + w * 32 + srow) * HD + gch * 8;
    const unsigned short* bq = kn + ((size_t)j * SEQ + w * 32 + srow) * HD + gch * 8;

#define STAGE(kt, b) do {                                            \
        const int kk_ = (kt) * 32;                                   \
        unsigned short* al_ = As + (b) * 8192 + w * 1024;            \
        unsigned short* bl_ = Bs + (b) * 8192 + w * 1024;            \
        glds16(aq + kk_,           al_);                             \
        glds16(aq + kk_ + 16 * HD, al_ + 512);                       \
        glds16(bq + kk_,           bl_);                             \
        glds16(bq + kk_ + 16 * HD, bl_ + 512);                       \
    } while (0)

    f32x4 acc[8][4];
    const f32x4 zero4 = {0.f, 0.f, 0.f, 0.f};
#pragma unroll
    for (int a = 0; a < 8; ++a)
#pragma unroll
        for (int b = 0; b < 4; ++b) acc[a][b] = zero4;

    // prologue: fill both buffers (8 glds in flight per wave)
    STAGE(0, 0);
    STAGE(1, 1);

    const int rsw = (ln >> 1) & 3;    // read-side chunk XOR (= f(row), row≡ln mod 16)

#pragma unroll 1
    for (int kt = 0; kt < NKT; ++kt) {
        const int cur = kt & 1;
        // tile kt landed (its 4 glds are oldest); keep tile kt+1 in flight
        if (kt == NKT - 1) asm volatile("s_waitcnt vmcnt(0)" ::: "memory");
        else               asm volatile("s_waitcnt vmcnt(4)" ::: "memory");
        __builtin_amdgcn_sched_barrier(0);
        __builtin_amdgcn_s_barrier();      // all waves' tile-kt writes visible

        const bf16x8* A8 = (const bf16x8*)(As + cur * 8192);
        const bf16x8* B8 = (const bf16x8*)(Bs + cur * 8192);
        bf16x8 af[8], bfr[4];
#pragma unroll
        for (int cn = 0; cn < 4; ++cn)
            bfr[cn] = B8[(wt * 64 + cn * 16 + ln) * 4 + (lg ^ rsw)];
#pragma unroll
        for (int rm = 0; rm < 8; ++rm)
            af[rm] = A8[(wsd * 128 + rm * 16 + ln) * 4 + (lg ^ rsw)];

        __builtin_amdgcn_s_setprio(1);
#pragma unroll
        for (int rm = 0; rm < 8; ++rm)
#pragma unroll
            for (int cn = 0; cn < 4; ++cn)
                acc[rm][cn] = __builtin_amdgcn_mfma_f32_16x16x32_bf16(
                    af[rm], bfr[cn], acc[rm][cn], 0, 0, 0);
        __builtin_amdgcn_s_setprio(0);

        __builtin_amdgcn_s_barrier();      // all waves done reading buf[cur]
        if (kt + 2 < NKT) STAGE(kt + 2, cur);   // 2-deep prefetch into freed buf
    }
#undef STAGE

    // epilogue: C/D layout col=ln (t), row=lg*4+r (s)
    __syncthreads();                    // all LDS traffic drained; reuse As
    float* zs  = (float*)As;            // [256][4] Z partials per (srow, wt)
    float* wsc = zs + 1024;             // [256][4] W partials

#pragma unroll
    for (int rm = 0; rm < 8; ++rm)
#pragma unroll
        for (int r = 0; r < 4; ++r) {
            int s = wsd * 128 + rm * 16 + lg * 4 + r;     // global s (full 256)
            float ze = 0.f, we = 0.f;
#pragma unroll
            for (int cn = 0; cn < 4; ++cn) {
                int t = wt * 64 + cn * 16 + ln;           // global t (full 256)
                float sim = acc[rm][cn][r];
                int d = s - t; d = (d < 0) ? -d : d;
                float e = kmB[t] * __expf(sim * w2[d]);
                ze += e;
                we = fmaf(e, sim, we);
            }
#pragma unroll
            for (int m = 1; m < 16; m <<= 1) {            // reduce over t-16 lanes
                ze += __shfl_xor(ze, m, 64);
                we += __shfl_xor(we, m, 64);
            }
            if (ln == 0) { zs[s * 4 + wt] = ze; wsc[s * 4 + wt] = we; }
        }
    __syncthreads();

    float part = 0.f;
    if (tid < 256) {
        const float4 Z4 = ((const float4*)zs)[tid];
        const float4 W4 = ((const float4*)wsc)[tid];
        float Z = Z4.x + Z4.y + Z4.z + Z4.w;
        float W = W4.x + W4.y + W4.z + W4.w;
        float pt = (Z > 0.f) ? (W / Z) : 0.f;
        part = pt * (float)q_mask[i * SEQ + tid];
    }
#pragma unroll
    for (int m = 1; m < 64; m <<= 1) part += __shfl_xor(part, m, 64);
    if (lane == 0) red[w] = part;
    __syncthreads();
    if (tid == 0) {
        float tot = red[0] + red[1] + red[2] + red[3]
                  + red[4] + red[5] + red[6] + red[7];
        out[i * BK2 + j] = tot;     // exactly one block per output element
    }
}

extern "C" void kernel_launch(void* const* d_in, const int* in_sizes, int n_in,
                              void* d_out, int out_size, void* d_ws, size_t ws_size,
                              hipStream_t stream) {
    const float* q  = (const float*)d_in[0];   // [16,256,768] f32
    const float* k  = (const float*)d_in[1];   // [32,256,768] f32
    const float* ls = (const float*)d_in[2];   // scalar
    const float* ar = (const float*)d_in[3];   // scalar
    const int* qm   = (const int*)d_in[4];     // [16,256]
    const int* km   = (const int*)d_in[5];     // [32,256]
    float* out      = (float*)d_out;           // [16,32] f32

    unsigned short* qn = (unsigned short*)d_ws;            // 16*256*768 bf16
    unsigned short* kn = qn + (size_t)BQ * SEQ * HD;       // 32*256*768 bf16

    norm_kernel<<<(BQ + BK2) * SEQ / 4, 256, 0, stream>>>(q, k, qn, kn);
    li_kernel<<<BK2 * BQ, 512, 0, stream>>>(qn, kn, ls, ar, qm, km, (float*)d_out);
}

// Round 4
// 151.092 us; speedup vs baseline: 4.0395x; 1.0674x over previous
//
#include <hip/hip_runtime.h>
#include <hip/hip_bf16.h>

#define BQ   16
#define BK2  32     // 2B
#define SEQ  256
#define HD   768
#define NKT  24     // HD / 32 K-tiles

typedef __attribute__((ext_vector_type(8))) short bf16x8;
typedef __attribute__((ext_vector_type(4))) float f32x4;

__device__ __forceinline__ void glds16(const unsigned short* g, unsigned short* l) {
    __builtin_amdgcn_global_load_lds(
        (const __attribute__((address_space(1))) unsigned int*)g,
        (__attribute__((address_space(3))) unsigned int*)l, 16, 0, 0);
}

// branch-free RNE fp32->bf16, packed two at a time
__device__ __forceinline__ unsigned int pack2_bf16(float a, float b) {
    unsigned ua = __float_as_uint(a), ub = __float_as_uint(b);
    ua += 0x7FFFu + ((ua >> 16) & 1u);
    ub += 0x7FFFu + ((ub >> 16) & 1u);
    return (ua >> 16) | (ub & 0xFFFF0000u);
}

// ---------------- Phase 1: fp32 l2-normalize -> bf16 (+ zero d_out) --------
__global__ __launch_bounds__(256) void norm_kernel(
    const float* __restrict__ q, const float* __restrict__ k,
    unsigned short* __restrict__ qn, unsigned short* __restrict__ kn,
    float* __restrict__ out)
{
    if (blockIdx.x == 0 && threadIdx.x < 256) {      // zero out for li's atomics
        out[threadIdx.x] = 0.f; out[threadIdx.x + 256] = 0.f;
    }
    int row  = blockIdx.x * 4 + (threadIdx.x >> 6);
    int lane = threadIdx.x & 63;
    const int NQ = BQ * SEQ;
    const float* src = (row < NQ) ? q + (size_t)row * HD
                                  : k + (size_t)(row - NQ) * HD;
    unsigned int* dst = (unsigned int*)((row < NQ) ? qn + (size_t)row * HD
                                                   : kn + (size_t)(row - NQ) * HD);
    float4 v[3];
    float ss = 0.f;
#pragma unroll
    for (int c = 0; c < 3; ++c) {
        v[c] = ((const float4*)src)[lane + 64 * c];
        ss += v[c].x * v[c].x + v[c].y * v[c].y + v[c].z * v[c].z + v[c].w * v[c].w;
    }
#pragma unroll
    for (int m = 1; m < 64; m <<= 1) ss += __shfl_xor(ss, m, 64);
    float inv = rsqrtf(fmaxf(ss, 1e-24f));
#pragma unroll
    for (int c = 0; c < 3; ++c) {
        uint2 o = make_uint2(pack2_bf16(v[c].x * inv, v[c].y * inv),
                             pack2_bf16(v[c].z * inv, v[c].w * inv));
        ((uint2*)dst)[lane + 64 * c] = o;
    }
}

// ---------------- Phase 2: block = (j, i, sh) covering 128 s x 256 t ------
// Round-0 geometry (proven 124 regs/wave -> 4 waves/SIMD, 2 blocks/CU TLP)
// + BK=32 double-buffered counted-vmcnt pipeline (never drains to 0 in-loop).
// 8 waves as 2(s) x 4(t) of 64x64 tiles; acc[4][4] = 64 AGPR.
// LDS chunk swizzle: chunk c of row r at slot c^((r>>1)&3), both-sides.
__global__ __launch_bounds__(512, 2) void li_kernel(
    const unsigned short* __restrict__ qn, const unsigned short* __restrict__ kn,
    const float* __restrict__ g_ls, const float* __restrict__ g_ar,
    const int* __restrict__ q_mask, const int* __restrict__ k_mask,
    float* __restrict__ out)
{
    // XCD-chunked bijective remap (1024 = 8 xcd * 4 jj * 16 i * 2 sh):
    // same-XCD blocks share 4 B-panels (1.5 MB) -> L2-hot.
    const int bid = blockIdx.x;
    const int xcd = bid & 7, local = bid >> 3;
    const int j  = xcd * 4 + (local >> 5);
    const int i  = (local >> 1) & 15;
    const int sh = local & 1;

    const int tid  = threadIdx.x;
    const int w    = tid >> 6, lane = tid & 63;
    const int ln   = lane & 15, lg = lane >> 4;
    const int wsd  = w >> 2, wt = w & 3;     // wave = (s-half, t-quarter)

    __shared__ __align__(16) unsigned short As[2 * 128 * 32];  // 16 KB dbuf
    __shared__ __align__(16) unsigned short Bs[2 * 256 * 32];  // 32 KB dbuf
    __shared__ float w2[SEQ];      // scale * exp(-alpha*d)
    __shared__ float kmB[SEQ];
    __shared__ float red[8];

    float a0 = g_ar[0];
    float alpha = (a0 > 0.f) ? a0 : 0.01f * a0;        // leaky_relu
    float scale = __expf(g_ls[0]);
    if (tid < 256) w2[tid] = scale * __expf(-alpha * (float)tid);
    else           kmB[tid - 256] = (k_mask[j * SEQ + (tid - 256)] != 0) ? 1.f : 0.f;

    // staging: per stage, wave w loads A rows [w*16,w*16+16) (1 glds) and
    // B rows [w*32,w*32+32) (2 glds). lane l: row base+(l>>2), LDS slot (l&3),
    // pre-swizzled source chunk (l&3)^((row>>1)&3).
    const int srow = lane >> 2;                       // 0..15 in 16-row group
    const int gch  = (lane & 3) ^ ((srow >> 1) & 3);
    const unsigned short* aq = qn + ((size_t)i * SEQ + sh * 128 + w * 16 + srow) * HD + gch * 8;
    const unsigned short* bq = kn + ((size_t)j * SEQ + w * 32 + srow) * HD + gch * 8;

#define STAGE(kt, b) do {                                            \
        const int kk_ = (kt) * 32;                                   \
        glds16(aq + kk_,           As + (b) * 4096 + w * 512);       \
        glds16(bq + kk_,           Bs + (b) * 8192 + w * 1024);      \
        glds16(bq + kk_ + 16 * HD, Bs + (b) * 8192 + w * 1024 + 512);\
    } while (0)

    f32x4 acc[4][4];
    const f32x4 zero4 = {0.f, 0.f, 0.f, 0.f};
#pragma unroll
    for (int a = 0; a < 4; ++a)
#pragma unroll
        for (int b = 0; b < 4; ++b) acc[a][b] = zero4;

    // prologue: fill both buffers (6 glds in flight per wave)
    STAGE(0, 0);
    STAGE(1, 1);

    const int rsw = (ln >> 1) & 3;    // read-side chunk XOR (row ≡ ln mod 16)

#define COMPUTE(A8, B8) do {                                               \
        bf16x8 af[4], bfr[4];                                              \
        _Pragma("unroll")                                                  \
        for (int cn = 0; cn < 4; ++cn)                                     \
            bfr[cn] = (B8)[(wt * 64 + cn * 16 + ln) * 4 + (lg ^ rsw)];     \
        _Pragma("unroll")                                                  \
        for (int rm = 0; rm < 4; ++rm)                                     \
            af[rm] = (A8)[(wsd * 64 + rm * 16 + ln) * 4 + (lg ^ rsw)];     \
        __builtin_amdgcn_s_setprio(1);                                     \
        _Pragma("unroll")                                                  \
        for (int rm = 0; rm < 4; ++rm)                                     \
            _Pragma("unroll")                                              \
            for (int cn = 0; cn < 4; ++cn)                                 \
                acc[rm][cn] = __builtin_amdgcn_mfma_f32_16x16x32_bf16(     \
                    af[rm], bfr[cn], acc[rm][cn], 0, 0, 0);                \
        __builtin_amdgcn_s_setprio(0);                                     \
    } while (0)

#pragma unroll 1
    for (int kt = 0; kt < NKT; kt += 2) {
        // ---- tile kt (buf 0): stages kt(3) + kt+1(3) outstanding ----
        asm volatile("s_waitcnt vmcnt(3)" ::: "memory");
        __builtin_amdgcn_sched_barrier(0);
        __builtin_amdgcn_s_barrier();
        COMPUTE((const bf16x8*)As, (const bf16x8*)Bs);
        __builtin_amdgcn_s_barrier();
        if (kt + 2 < NKT) STAGE(kt + 2, 0);
        // ---- tile kt+1 (buf 1) ----
        if (kt + 2 < NKT) asm volatile("s_waitcnt vmcnt(3)" ::: "memory");
        else              asm volatile("s_waitcnt vmcnt(0)" ::: "memory");
        __builtin_amdgcn_sched_barrier(0);
        __builtin_amdgcn_s_barrier();
        COMPUTE((const bf16x8*)(As + 4096), (const bf16x8*)(Bs + 8192));
        __builtin_amdgcn_s_barrier();
        if (kt + 3 < NKT) STAGE(kt + 3, 1);
    }
#undef COMPUTE
#undef STAGE

    // epilogue: C/D layout col=ln (t), row=lg*4+r (s)
    __syncthreads();                    // all LDS traffic drained; reuse As
    float* zs  = (float*)As;            // [128][4] Z partials per (srow, wt)
    float* wsc = zs + 512;              // [128][4] W partials

#pragma unroll
    for (int rm = 0; rm < 4; ++rm)
#pragma unroll
        for (int r = 0; r < 4; ++r) {
            int srow = wsd * 64 + rm * 16 + lg * 4 + r;   // s within block's 128
            int s  = sh * 128 + srow;
            float ze = 0.f, we = 0.f;
#pragma unroll
            for (int cn = 0; cn < 4; ++cn) {
                int t = wt * 64 + cn * 16 + ln;           // global t (full 256)
                float sim = acc[rm][cn][r];
                int d = s - t; d = (d < 0) ? -d : d;
                float e = kmB[t] * __expf(sim * w2[d]);
                ze += e;
                we = fmaf(e, sim, we);
            }
#pragma unroll
            for (int m = 1; m < 16; m <<= 1) {            // reduce over t-16 lanes
                ze += __shfl_xor(ze, m, 64);
                we += __shfl_xor(we, m, 64);
            }
            if (ln == 0) { zs[srow * 4 + wt] = ze; wsc[srow * 4 + wt] = we; }
        }
    __syncthreads();

    float part = 0.f;
    if (tid < 128) {
        const float4 Z4 = ((const float4*)zs)[tid];
        const float4 W4 = ((const float4*)wsc)[tid];
        float Z = Z4.x + Z4.y + Z4.z + Z4.w;
        float W = W4.x + W4.y + W4.z + W4.w;
        float pt = (Z > 0.f) ? (W / Z) : 0.f;
        part = pt * (float)q_mask[i * SEQ + sh * 128 + tid];
    }
#pragma unroll
    for (int m = 1; m < 64; m <<= 1) part += __shfl_xor(part, m, 64);
    if (lane == 0) red[w] = part;
    __syncthreads();
    if (tid == 0) {
        float tot = red[0] + red[1] + red[2] + red[3]
                  + red[4] + red[5] + red[6] + red[7];
        atomicAdd(&out[i * BK2 + j], tot);
    }
}

extern "C" void kernel_launch(void* const* d_in, const int* in_sizes, int n_in,
                              void* d_out, int out_size, void* d_ws, size_t ws_size,
                              hipStream_t stream) {
    const float* q  = (const float*)d_in[0];   // [16,256,768] f32
    const float* k  = (const float*)d_in[1];   // [32,256,768] f32
    const float* ls = (const float*)d_in[2];   // scalar
    const float* ar = (const float*)d_in[3];   // scalar
    const int* qm   = (const int*)d_in[4];     // [16,256]
    const int* km   = (const int*)d_in[5];     // [32,256]
    float* out      = (float*)d_out;           // [16,32] f32

    unsigned short* qn = (unsigned short*)d_ws;            // 16*256*768 bf16
    unsigned short* kn = qn + (size_t)BQ * SEQ * HD;       // 32*256*768 bf16

    norm_kernel<<<(BQ + BK2) * SEQ / 4, 256, 0, stream>>>(q, k, qn, kn, (float*)d_out);
    li_kernel<<<BK2 * BQ * 2, 512, 0, stream>>>(qn, kn, ls, ar, qm, km, (float*)d_out);
}

// Round 5
// 148.988 us; speedup vs baseline: 4.0965x; 1.0141x over previous
//
#include <hip/hip_runtime.h>
#include <hip/hip_bf16.h>

#define BQ   16
#define BK2  32     // 2B
#define SEQ  256
#define HD   768
#define NKT  12     // HD / 64 K-tiles

typedef __attribute__((ext_vector_type(8))) short bf16x8;
typedef __attribute__((ext_vector_type(4))) float f32x4;

__device__ __forceinline__ void glds16(const unsigned short* g, unsigned short* l) {
    __builtin_amdgcn_global_load_lds(
        (const __attribute__((address_space(1))) unsigned int*)g,
        (__attribute__((address_space(3))) unsigned int*)l, 16, 0, 0);
}

// branch-free RNE fp32->bf16, packed two at a time
__device__ __forceinline__ unsigned int pack2_bf16(float a, float b) {
    unsigned ua = __float_as_uint(a), ub = __float_as_uint(b);
    ua += 0x7FFFu + ((ua >> 16) & 1u);
    ub += 0x7FFFu + ((ub >> 16) & 1u);
    return (ua >> 16) | (ub & 0xFFFF0000u);
}

// ---------------- Phase 1: fp32 l2-normalize -> bf16 ----------------------
__global__ __launch_bounds__(256) void norm_kernel(
    const float* __restrict__ q, const float* __restrict__ k,
    unsigned short* __restrict__ qn, unsigned short* __restrict__ kn)
{
    int row  = blockIdx.x * 4 + (threadIdx.x >> 6);
    int lane = threadIdx.x & 63;
    const int NQ = BQ * SEQ;
    const float* src = (row < NQ) ? q + (size_t)row * HD
                                  : k + (size_t)(row - NQ) * HD;
    unsigned int* dst = (unsigned int*)((row < NQ) ? qn + (size_t)row * HD
                                                   : kn + (size_t)(row - NQ) * HD);
    float4 v[3];
    float ss = 0.f;
#pragma unroll
    for (int c = 0; c < 3; ++c) {
        v[c] = ((const float4*)src)[lane + 64 * c];
        ss += v[c].x * v[c].x + v[c].y * v[c].y + v[c].z * v[c].z + v[c].w * v[c].w;
    }
#pragma unroll
    for (int m = 1; m < 64; m <<= 1) ss += __shfl_xor(ss, m, 64);
    float inv = rsqrtf(fmaxf(ss, 1e-24f));
#pragma unroll
    for (int c = 0; c < 3; ++c) {
        uint2 o = make_uint2(pack2_bf16(v[c].x * inv, v[c].y * inv),
                             pack2_bf16(v[c].z * inv, v[c].w * inv));
        ((uint2*)dst)[lane + 64 * c] = o;
    }
}

// ---------------- Phase 2: block = (j, i) covering FULL 256 s x 256 t -----
// 256^2-template port: BK=64, 8 waves 2(s)x4(t), per-wave 128x64 (acc[8][4]),
// A/B double-buffered in LDS (128 KB, 1 block/CU). Counted vmcnt(8) steady
// state (never drains in-loop), stage-after-compute, raw s_barrier,
// 64 MFMA per barrier-pair per wave, setprio around MFMA cluster.
// Chunk swizzle (proven 0-conflict in r0/r3): logical 16B-chunk c of row r
// stored at slot c^(r&7); pre-swizzled global source, linear glds dest.
// One block per output element -> direct store, no atomics.
__global__ __launch_bounds__(512, 2) void li_kernel(
    const unsigned short* __restrict__ qn, const unsigned short* __restrict__ kn,
    const float* __restrict__ g_ls, const float* __restrict__ g_ar,
    const int* __restrict__ q_mask, const int* __restrict__ k_mask,
    float* __restrict__ out)
{
    // XCD-aware bijective remap: xcd = bid&7 owns an 8x8 (i,j) sub-rectangle.
    const int bid   = blockIdx.x;
    const int xcd   = bid & 7, local = bid >> 3;        // local 0..63
    const int i = (xcd & 1) * 8 + (local >> 3);         // 0..15
    const int j = (xcd >> 1) * 8 + (local & 7);         // 0..31

    const int tid  = threadIdx.x;
    const int w    = tid >> 6, lane = tid & 63;
    const int ln   = lane & 15, lg = lane >> 4;
    const int wsd  = w >> 2, wt = w & 3;     // wave = (s-half, t-quarter)

    __shared__ __align__(16) unsigned short As[2 * 256 * 64];  // 64 KB dbuf
    __shared__ __align__(16) unsigned short Bs[2 * 256 * 64];  // 64 KB dbuf
    __shared__ float w2[SEQ];      // scale * exp(-alpha*d)
    __shared__ float kmB[SEQ];
    __shared__ float red[8];

    float a0 = g_ar[0];
    float alpha = (a0 > 0.f) ? a0 : 0.01f * a0;        // leaky_relu
    float scale = __expf(g_ls[0]);
    if (tid < 256) w2[tid] = scale * __expf(-alpha * (float)tid);
    else           kmB[tid - 256] = (k_mask[j * SEQ + (tid - 256)] != 0) ? 1.f : 0.f;

    // staging: per K-tile, wave w stages rows [w*32, w*32+32) of A and B
    // (4 glds each, 8 rows per glds). lane l: row sub-index rl = l>>3,
    // LDS slot (l&7), pre-swizzled source chunk (l&7)^rl  (row&7 == rl).
    const int rl  = lane >> 3;
    const int gch = (lane & 7) ^ rl;
    const unsigned short* aq = qn + ((size_t)i * SEQ + w * 32 + rl) * HD + gch * 8;
    const unsigned short* bq = kn + ((size_t)j * SEQ + w * 32 + rl) * HD + gch * 8;

#define STAGE(kt, b) do {                                                     \
        const int kk_ = (kt) * 64;                                            \
        _Pragma("unroll")                                                     \
        for (int g = 0; g < 4; ++g) {                                         \
            glds16(aq + kk_ + g * (8 * HD),                                   \
                   As + (b) * 16384 + (w * 32 + g * 8) * 64);                 \
            glds16(bq + kk_ + g * (8 * HD),                                   \
                   Bs + (b) * 16384 + (w * 32 + g * 8) * 64);                 \
        }                                                                     \
    } while (0)

    f32x4 acc[8][4];
    const f32x4 zero4 = {0.f, 0.f, 0.f, 0.f};
#pragma unroll
    for (int a = 0; a < 8; ++a)
#pragma unroll
        for (int b = 0; b < 4; ++b) acc[a][b] = zero4;

    __syncthreads();               // w2/kmB visible to all waves (before glds!)

    // prologue: fill both buffers (16 glds in flight per wave)
    STAGE(0, 0);
    STAGE(1, 1);

    // one K-tile: 2 k-slices x (8x4) MFMAs = 64 MFMA, 24 ds_read_b128
#define COMPUTE(b) do {                                                       \
        const bf16x8* A8 = (const bf16x8*)(As + (b) * 16384);                 \
        const bf16x8* B8 = (const bf16x8*)(Bs + (b) * 16384);                 \
        _Pragma("unroll")                                                     \
        for (int ks = 0; ks < 2; ++ks) {                                      \
            const int sl = (ks * 4 + lg) ^ (ln & 7);  /* unswizzle slot */    \
            bf16x8 af[8], bfr[4];                                             \
            _Pragma("unroll")                                                 \
            for (int cn = 0; cn < 4; ++cn)                                    \
                bfr[cn] = B8[(wt * 64 + cn * 16 + ln) * 8 + sl];              \
            _Pragma("unroll")                                                 \
            for (int rm = 0; rm < 8; ++rm)                                    \
                af[rm] = A8[(wsd * 128 + rm * 16 + ln) * 8 + sl];             \
            __builtin_amdgcn_s_setprio(1);                                    \
            _Pragma("unroll")                                                 \
            for (int rm = 0; rm < 8; ++rm)                                    \
                _Pragma("unroll")                                             \
                for (int cn = 0; cn < 4; ++cn)                                \
                    acc[rm][cn] = __builtin_amdgcn_mfma_f32_16x16x32_bf16(    \
                        af[rm], bfr[cn], acc[rm][cn], 0, 0, 0);               \
            __builtin_amdgcn_s_setprio(0);                                    \
        }                                                                     \
    } while (0)

#pragma unroll 1
    for (int kt = 0; kt < NKT; kt += 2) {
        // ---- tile kt (buf 0): 16 outstanding; oldest 8 = tile kt ----
        asm volatile("s_waitcnt vmcnt(8)" ::: "memory");
        __builtin_amdgcn_sched_barrier(0);
        __builtin_amdgcn_s_barrier();
        COMPUTE(0);
        __builtin_amdgcn_s_barrier();          // all waves done reading buf 0
        if (kt + 2 < NKT) STAGE(kt + 2, 0);
        // ---- tile kt+1 (buf 1) ----
        if (kt + 3 < NKT) asm volatile("s_waitcnt vmcnt(8)" ::: "memory");
        else              asm volatile("s_waitcnt vmcnt(0)" ::: "memory");
        __builtin_amdgcn_sched_barrier(0);
        __builtin_amdgcn_s_barrier();
        COMPUTE(1);
        __builtin_amdgcn_s_barrier();          // all waves done reading buf 1
        if (kt + 3 < NKT) STAGE(kt + 3, 1);
    }
#undef COMPUTE
#undef STAGE

    // epilogue: C/D layout col=ln (t), row=lg*4+r (s)   [verified in r2/r3]
    __syncthreads();                    // full drain; reuse As as scratch
    float* zs  = (float*)As;            // [256][4] Z partials per (s, wt)
    float* wsc = zs + 1024;             // [256][4] W partials

#pragma unroll
    for (int rm = 0; rm < 8; ++rm)
#pragma unroll
        for (int r = 0; r < 4; ++r) {
            int s = wsd * 128 + rm * 16 + lg * 4 + r;     // global s (full 256)
            float ze = 0.f, we = 0.f;
#pragma unroll
            for (int cn = 0; cn < 4; ++cn) {
                int t = wt * 64 + cn * 16 + ln;           // global t (full 256)
                float sim = acc[rm][cn][r];
                int d = s - t; d = (d < 0) ? -d : d;
                float e = kmB[t] * __expf(sim * w2[d]);
                ze += e;
                we = fmaf(e, sim, we);
            }
#pragma unroll
            for (int m = 1; m < 16; m <<= 1) {            // reduce over t-16 lanes
                ze += __shfl_xor(ze, m, 64);
                we += __shfl_xor(we, m, 64);
            }
            if (ln == 0) { zs[s * 4 + wt] = ze; wsc[s * 4 + wt] = we; }
        }
    __syncthreads();

    float part = 0.f;
    if (tid < 256) {
        const float4 Z4 = ((const float4*)zs)[tid];
        const float4 W4 = ((const float4*)wsc)[tid];
        float Z = Z4.x + Z4.y + Z4.z + Z4.w;
        float W = W4.x + W4.y + W4.z + W4.w;
        float pt = (Z > 0.f) ? (W / Z) : 0.f;
        part = pt * (float)q_mask[i * SEQ + tid];
    }
#pragma unroll
    for (int m = 1; m < 64; m <<= 1) part += __shfl_xor(part, m, 64);
    if (lane == 0) red[w] = part;
    __syncthreads();
    if (tid == 0) {
        float tot = red[0] + red[1] + red[2] + red[3]
                  + red[4] + red[5] + red[6] + red[7];
        out[i * BK2 + j] = tot;     // exactly one block per output element
    }
}

extern "C" void kernel_launch(void* const* d_in, const int* in_sizes, int n_in,
                              void* d_out, int out_size, void* d_ws, size_t ws_size,
                              hipStream_t stream) {
    const float* q  = (const float*)d_in[0];   // [16,256,768] f32
    const float* k  = (const float*)d_in[1];   // [32,256,768] f32
    const float* ls = (const float*)d_in[2];   // scalar
    const float* ar = (const float*)d_in[3];   // scalar
    const int* qm   = (const int*)d_in[4];     // [16,256]
    const int* km   = (const int*)d_in[5];     // [32,256]
    float* out      = (float*)d_out;           // [16,32] f32

    unsigned short* qn = (unsigned short*)d_ws;            // 16*256*768 bf16
    unsigned short* kn = qn + (size_t)BQ * SEQ * HD;       // 32*256*768 bf16

    norm_kernel<<<(BQ + BK2) * SEQ / 4, 256, 0, stream>>>(q, k, qn, kn);
    li_kernel<<<BK2 * BQ, 512, 0, stream>>>(qn, kn, ls, ar, qm, km, (float*)d_out);
}